// Round 16
// baseline (146.219 us; speedup 1.0000x reference)
//
#include <hip/hip_runtime.h>

typedef _Float16 f16;
typedef _Float16 f16x4 __attribute__((ext_vector_type(4)));
typedef _Float16 f16x8 __attribute__((ext_vector_type(8)));
typedef float f32x4 __attribute__((ext_vector_type(4)));

#define N_NODES 50000
#define N_EDGES 800000
#define N_CLASSES 10
#define CAP 64           // per-node bucket capacity; deg~Poisson(16), P(>=64)~e^-128
#define EDGE_BLOCKS ((N_EDGES + 255) / 256)        // 3125; == x-convert chunks of 8

// ---------------------------------------------------------------------------
// Zero the degree counters (~2us; rocclr fillBuffer was ~40us)
// ---------------------------------------------------------------------------
__global__ void zero_cnt_kernel(int* __restrict__ cnt) {
    int i = blockIdx.x * 256 + threadIdx.x;
    if (i < N_NODES / 4) ((int4*)cnt)[i] = make_int4(0, 0, 0, 0);
}

// ---------------------------------------------------------------------------
// Fused build, thread-level overlap: each thread owns 1 edge (atomic-latency
// chain) + 8 x-elements (f32->f16 convert). The convert loads/stores are
// independent of the atomic chain, so they fill the atomic round-trip shadow
// within the thread — no reliance on block scheduling. 800k threads cover
// both 800k edges and 6.4M x elements exactly. Tail blocks pack weights.
// ---------------------------------------------------------------------------
__global__ void build_fused_kernel(const int* __restrict__ src, const int* __restrict__ dst,
                                   int* __restrict__ cnt, unsigned short* __restrict__ bucket,
                                   const float* __restrict__ x,
                                   const float* __restrict__ w1l, const float* __restrict__ w1r,
                                   const float* __restrict__ w2l, const float* __restrict__ w2r,
                                   f16* __restrict__ xh, f16* __restrict__ W1, f16* __restrict__ W2cat) {
    int bid = blockIdx.x;
    if (bid < EDGE_BLOCKS) {
        long long i = (long long)bid * 256 + threadIdx.x;   // 0..799999
        // independent loads first: edge endpoints + x chunk
        int d = dst[i];
        int sv = src[i];
        float4 a = *(const float4*)(x + i * 8);
        float4 b = *(const float4*)(x + i * 8 + 4);
        // atomic chain (latency hidden by the convert work below)
        int s = atomicAdd(&cnt[d], 1);
        // convert + store (no dependence on s)
        f16x8 o;
        o[0] = (f16)a.x; o[1] = (f16)a.y; o[2] = (f16)a.z; o[3] = (f16)a.w;
        o[4] = (f16)b.x; o[5] = (f16)b.y; o[6] = (f16)b.z; o[7] = (f16)b.w;
        *(f16x8*)(xh + i * 8) = o;
        // bucket placement
        if (s < CAP) bucket[(long long)d * CAP + s] = (unsigned short)sv;
    } else {
        int wt = (bid - EDGE_BLOCKS) * 256 + threadIdx.x;   // 0..1023
        for (int idx = wt; idx < 128 * 256; idx += 1024) {
            int n = idx >> 8, k = idx & 255;
            W1[idx] = (f16)(k < 128 ? w1l[n * 128 + k] : w1r[n * 128 + k - 128]);
        }
        for (int idx = wt; idx < 128 * 128; idx += 1024) {
            int n = idx >> 7, k = idx & 127;
            W2cat[idx] = (f16)(n < 64 ? w2l[n * 128 + k] : w2r[(n - 64) * 128 + k]);
        }
    }
}

// ---------------------------------------------------------------------------
// Layer-1 aggregation (R11-proven): 2 nodes/wave, 32 lanes x f16x4 (8B).
// ---------------------------------------------------------------------------
__global__ void agg_mean_f16_kernel(const f16* __restrict__ feat,
                                    const int* __restrict__ cnt,
                                    const unsigned short* __restrict__ bucket,
                                    f16* __restrict__ outb) {
    int node = blockIdx.x * 8 + (threadIdx.x >> 5);
    int l  = threadIdx.x & 31;
    int bl = threadIdx.x & 32;
    int deg = cnt[node];
    int n_it = deg < CAP ? deg : CAP;
    const unsigned short* b = bucket + (long long)node * CAP;
    int my0 = (l < n_it)      ? (int)b[l]      : 0;
    int my1 = (32 + l < n_it) ? (int)b[32 + l] : 0;
    const f16x4* f4 = (const f16x4*)feat;
    float a0 = 0.f, a1 = 0.f, a2 = 0.f, a3 = 0.f;
    int j = 0;
    int lim0 = n_it < 32 ? n_it : 32;
    for (; j + 8 <= lim0; j += 8) {
        f16x4 v0 = f4[(long long)__shfl(my0, bl + j + 0) * 32 + l];
        f16x4 v1 = f4[(long long)__shfl(my0, bl + j + 1) * 32 + l];
        f16x4 v2 = f4[(long long)__shfl(my0, bl + j + 2) * 32 + l];
        f16x4 v3 = f4[(long long)__shfl(my0, bl + j + 3) * 32 + l];
        f16x4 v4 = f4[(long long)__shfl(my0, bl + j + 4) * 32 + l];
        f16x4 v5 = f4[(long long)__shfl(my0, bl + j + 5) * 32 + l];
        f16x4 v6 = f4[(long long)__shfl(my0, bl + j + 6) * 32 + l];
        f16x4 v7 = f4[(long long)__shfl(my0, bl + j + 7) * 32 + l];
        a0 += (((float)v0[0] + (float)v1[0]) + ((float)v2[0] + (float)v3[0]))
            + (((float)v4[0] + (float)v5[0]) + ((float)v6[0] + (float)v7[0]));
        a1 += (((float)v0[1] + (float)v1[1]) + ((float)v2[1] + (float)v3[1]))
            + (((float)v4[1] + (float)v5[1]) + ((float)v6[1] + (float)v7[1]));
        a2 += (((float)v0[2] + (float)v1[2]) + ((float)v2[2] + (float)v3[2]))
            + (((float)v4[2] + (float)v5[2]) + ((float)v6[2] + (float)v7[2]));
        a3 += (((float)v0[3] + (float)v1[3]) + ((float)v2[3] + (float)v3[3]))
            + (((float)v4[3] + (float)v5[3]) + ((float)v6[3] + (float)v7[3]));
    }
    for (; j < lim0; j++) {
        f16x4 v = f4[(long long)__shfl(my0, bl + j) * 32 + l];
        a0 += (float)v[0]; a1 += (float)v[1]; a2 += (float)v[2]; a3 += (float)v[3];
    }
    for (; j + 8 <= n_it; j += 8) {
        f16x4 v0 = f4[(long long)__shfl(my1, bl + j - 32 + 0) * 32 + l];
        f16x4 v1 = f4[(long long)__shfl(my1, bl + j - 32 + 1) * 32 + l];
        f16x4 v2 = f4[(long long)__shfl(my1, bl + j - 32 + 2) * 32 + l];
        f16x4 v3 = f4[(long long)__shfl(my1, bl + j - 32 + 3) * 32 + l];
        f16x4 v4 = f4[(long long)__shfl(my1, bl + j - 32 + 4) * 32 + l];
        f16x4 v5 = f4[(long long)__shfl(my1, bl + j - 32 + 5) * 32 + l];
        f16x4 v6 = f4[(long long)__shfl(my1, bl + j - 32 + 6) * 32 + l];
        f16x4 v7 = f4[(long long)__shfl(my1, bl + j - 32 + 7) * 32 + l];
        a0 += (((float)v0[0] + (float)v1[0]) + ((float)v2[0] + (float)v3[0]))
            + (((float)v4[0] + (float)v5[0]) + ((float)v6[0] + (float)v7[0]));
        a1 += (((float)v0[1] + (float)v1[1]) + ((float)v2[1] + (float)v3[1]))
            + (((float)v4[1] + (float)v5[1]) + ((float)v6[1] + (float)v7[1]));
        a2 += (((float)v0[2] + (float)v1[2]) + ((float)v2[2] + (float)v3[2]))
            + (((float)v4[2] + (float)v5[2]) + ((float)v6[2] + (float)v7[2]));
        a3 += (((float)v0[3] + (float)v1[3]) + ((float)v2[3] + (float)v3[3]))
            + (((float)v4[3] + (float)v5[3]) + ((float)v6[3] + (float)v7[3]));
    }
    for (; j < n_it; j++) {
        f16x4 v = f4[(long long)__shfl(my1, bl + j - 32) * 32 + l];
        a0 += (float)v[0]; a1 += (float)v[1]; a2 += (float)v[2]; a3 += (float)v[3];
    }
    float inv = 1.f / fmaxf((float)deg, 1.f);
    f16x4 r;
    r[0] = (f16)(a0 * inv); r[1] = (f16)(a1 * inv);
    r[2] = (f16)(a2 * inv); r[3] = (f16)(a3 * inv);
    ((f16x4*)outb)[(long long)node * 32 + l] = r;
}

// ---------------------------------------------------------------------------
// Fused layer-1 + layer-2 pre-transform (R13-proven):
// Stage 1: h1 = relu(bn1(mean@W1l^T+b1+x@W1r^T)) -> per-wave LDS tile
// Stage 2: y2 = [h1@W2l^T | h1@W2r^T] -> global (h1 never hits HBM).
// ---------------------------------------------------------------------------
__global__ __launch_bounds__(256) void sage1_y2_kernel(
    const f16* __restrict__ Am, const f16* __restrict__ Ax,
    const f16* __restrict__ W1,
    const float* __restrict__ bias, const float* __restrict__ gamma,
    const float* __restrict__ beta, const float* __restrict__ bmean,
    const float* __restrict__ bvar,
    const f16* __restrict__ W2cat,  // [128][128]
    f16* __restrict__ y2) {
    __shared__ f16 ldsA[4][32][136];

    int tid  = threadIdx.x;
    int wave = tid >> 6;
    int lane = tid & 63;
    int m_base = blockIdx.x * 128 + wave * 32;
    int lrow = lane & 15;
    int lchunk = lane >> 4;

    f32x4 acc[2][8] = {};

#pragma unroll
    for (int phase = 0; phase < 2; phase++) {
        const f16* A = phase ? Ax : Am;
        const f16* Wp = W1 + phase * 128;
        f16x8 afrag[4][2];
#pragma unroll
        for (int kc = 0; kc < 4; kc++)
#pragma unroll
            for (int mf = 0; mf < 2; mf++) {
                int row = m_base + mf * 16 + lrow;
                row = row < N_NODES ? row : N_NODES - 1;
                afrag[kc][mf] = *(const f16x8*)(A + (long long)row * 128 + kc * 32 + lchunk * 8);
            }
#pragma unroll
        for (int nf = 0; nf < 8; nf++)
#pragma unroll
            for (int kc = 0; kc < 4; kc++) {
                f16x8 b = *(const f16x8*)(Wp + (long long)(nf * 16 + lrow) * 256
                                          + kc * 32 + lchunk * 8);
                acc[0][nf] = __builtin_amdgcn_mfma_f32_16x16x32_f16(afrag[kc][0], b, acc[0][nf], 0, 0, 0);
                acc[1][nf] = __builtin_amdgcn_mfma_f32_16x16x32_f16(afrag[kc][1], b, acc[1][nf], 0, 0, 0);
            }
    }

    // BN1 + ReLU -> per-wave LDS tile
#pragma unroll
    for (int nf = 0; nf < 8; nf++) {
        int n = nf * 16 + lrow;
        float mul = gamma[n] * rsqrtf(bvar[n] + 1e-5f);
        float add = (bias[n] - bmean[n]) * mul + beta[n];
#pragma unroll
        for (int mf = 0; mf < 2; mf++)
#pragma unroll
            for (int r = 0; r < 4; r++) {
                int rloc = mf * 16 + lchunk * 4 + r;
                ldsA[wave][rloc][n] = (f16)fmaxf(fmaf(acc[mf][nf][r], mul, add), 0.f);
            }
    }

    // Stage 2: y2 = h1_tile @ W2cat^T (K=128)
#pragma unroll
    for (int nf2 = 0; nf2 < 8; nf2++) {
        f32x4 acc2[2] = {};
#pragma unroll
        for (int kc = 0; kc < 4; kc++) {
            f16x8 b2 = *(const f16x8*)(W2cat + (long long)(nf2 * 16 + lrow) * 128
                                       + kc * 32 + lchunk * 8);
            f16x8 a0 = *(const f16x8*)&ldsA[wave][lrow][kc * 32 + lchunk * 8];
            f16x8 a1 = *(const f16x8*)&ldsA[wave][16 + lrow][kc * 32 + lchunk * 8];
            acc2[0] = __builtin_amdgcn_mfma_f32_16x16x32_f16(a0, b2, acc2[0], 0, 0, 0);
            acc2[1] = __builtin_amdgcn_mfma_f32_16x16x32_f16(a1, b2, acc2[1], 0, 0, 0);
        }
        int n = nf2 * 16 + lrow;
#pragma unroll
        for (int mf = 0; mf < 2; mf++)
#pragma unroll
            for (int r = 0; r < 4; r++) {
                int m = m_base + mf * 16 + lchunk * 4 + r;
                if (m < N_NODES) y2[(long long)m * 128 + n] = (f16)acc2[mf][r];
            }
    }
}

// ---------------------------------------------------------------------------
// Fused layer-2 aggregation + BN2 + ReLU + head (R14-proven). 16 nodes/block,
// 3125 blocks. No LDS, no syncthreads.
// ---------------------------------------------------------------------------
__global__ void agg2_head_kernel(const f16* __restrict__ y2,
                                 const int* __restrict__ cnt,
                                 const unsigned short* __restrict__ bucket,
                                 const float* __restrict__ b2,
                                 const float* __restrict__ gamma,
                                 const float* __restrict__ beta,
                                 const float* __restrict__ bmean,
                                 const float* __restrict__ bvar,
                                 const float* __restrict__ hw,
                                 const float* __restrict__ hb,
                                 float* __restrict__ outp) {
    int node = blockIdx.x * 16 + (threadIdx.x >> 4);
    int l  = threadIdx.x & 15;
    int bl = threadIdx.x & 48;
    int deg = cnt[node];
    int n_it = deg < CAP ? deg : CAP;
    const unsigned short* b = bucket + (long long)node * CAP;
    int my0 = (l < n_it)      ? (int)b[l]      : 0;
    int my1 = (16 + l < n_it) ? (int)b[16 + l] : 0;
    int my2 = (32 + l < n_it) ? (int)b[32 + l] : 0;
    int my3 = (48 + l < n_it) ? (int)b[48 + l] : 0;
    const f16x4* f4 = (const f16x4*)y2;
    float a0 = 0.f, a1 = 0.f, a2 = 0.f, a3 = 0.f;
    int j = 0;

#define AGG_SEC(MYREG, BASE)                                                     \
    {                                                                            \
        int lim = n_it < (BASE + 16) ? n_it : (BASE + 16);                       \
        for (; j + 8 <= lim; j += 8) {                                           \
            f16x4 v0 = f4[(long long)__shfl(MYREG, bl + j - BASE + 0) * 32 + l]; \
            f16x4 v1 = f4[(long long)__shfl(MYREG, bl + j - BASE + 1) * 32 + l]; \
            f16x4 v2 = f4[(long long)__shfl(MYREG, bl + j - BASE + 2) * 32 + l]; \
            f16x4 v3 = f4[(long long)__shfl(MYREG, bl + j - BASE + 3) * 32 + l]; \
            f16x4 v4 = f4[(long long)__shfl(MYREG, bl + j - BASE + 4) * 32 + l]; \
            f16x4 v5 = f4[(long long)__shfl(MYREG, bl + j - BASE + 5) * 32 + l]; \
            f16x4 v6 = f4[(long long)__shfl(MYREG, bl + j - BASE + 6) * 32 + l]; \
            f16x4 v7 = f4[(long long)__shfl(MYREG, bl + j - BASE + 7) * 32 + l]; \
            a0 += (((float)v0[0] + (float)v1[0]) + ((float)v2[0] + (float)v3[0]))\
                + (((float)v4[0] + (float)v5[0]) + ((float)v6[0] + (float)v7[0]));\
            a1 += (((float)v0[1] + (float)v1[1]) + ((float)v2[1] + (float)v3[1]))\
                + (((float)v4[1] + (float)v5[1]) + ((float)v6[1] + (float)v7[1]));\
            a2 += (((float)v0[2] + (float)v1[2]) + ((float)v2[2] + (float)v3[2]))\
                + (((float)v4[2] + (float)v5[2]) + ((float)v6[2] + (float)v7[2]));\
            a3 += (((float)v0[3] + (float)v1[3]) + ((float)v2[3] + (float)v3[3]))\
                + (((float)v4[3] + (float)v5[3]) + ((float)v6[3] + (float)v7[3]));\
        }                                                                        \
        for (; j < lim; j++) {                                                   \
            f16x4 v = f4[(long long)__shfl(MYREG, bl + j - BASE) * 32 + l];      \
            a0 += (float)v[0]; a1 += (float)v[1];                                \
            a2 += (float)v[2]; a3 += (float)v[3];                                \
        }                                                                        \
    }

    AGG_SEC(my0, 0)
    AGG_SEC(my1, 16)
    AGG_SEC(my2, 32)
    AGG_SEC(my3, 48)
#undef AGG_SEC

    // BN2 + ReLU in f32 (channels 4l..4l+3 of this node)
    float inv = 1.f / fmaxf((float)deg, 1.f);
    f16x4 yr = f4[(long long)node * 32 + 16 + l];   // y2r quad
    float h[4];
#pragma unroll
    for (int i = 0; i < 4; i++) {
        int n = l * 4 + i;
        float mul = gamma[n] * rsqrtf(bvar[n] + 1e-5f);
        float add = (b2[n] - bmean[n]) * mul + beta[n];
        float a = (i == 0 ? a0 : i == 1 ? a1 : i == 2 ? a2 : a3);
        h[i] = fmaxf(fmaf(a * inv + (float)yr[i], mul, add), 0.f);
    }

    // head: 10 logits, 16-lane group reduce per class
#pragma unroll
    for (int c = 0; c < N_CLASSES; c++) {
        const float* w = hw + c * 64 + l * 4;
        float p = h[0] * w[0] + h[1] * w[1] + h[2] * w[2] + h[3] * w[3];
        p += __shfl_xor(p, 8);
        p += __shfl_xor(p, 4);
        p += __shfl_xor(p, 2);
        p += __shfl_xor(p, 1);
        if (l == c) outp[(long long)node * N_CLASSES + c] = p + hb[c];
    }
}

// ---------------------------------------------------------------------------
extern "C" void kernel_launch(void* const* d_in, const int* in_sizes, int n_in,
                              void* d_out, int out_size, void* d_ws, size_t ws_size,
                              hipStream_t stream) {
    const float* x      = (const float*)d_in[0];
    const int*   ei     = (const int*)d_in[1];
    const float* w1l    = (const float*)d_in[2];
    const float* b1l    = (const float*)d_in[3];
    const float* w1r    = (const float*)d_in[4];
    const float* bn1_g  = (const float*)d_in[5];
    const float* bn1_b  = (const float*)d_in[6];
    const float* bn1_m  = (const float*)d_in[7];
    const float* bn1_v  = (const float*)d_in[8];
    const float* w2l    = (const float*)d_in[9];
    const float* b2l    = (const float*)d_in[10];
    const float* w2r    = (const float*)d_in[11];
    const float* bn2_g  = (const float*)d_in[12];
    const float* bn2_b  = (const float*)d_in[13];
    const float* bn2_m  = (const float*)d_in[14];
    const float* bn2_v  = (const float*)d_in[15];
    const float* head_w = (const float*)d_in[16];
    const float* head_b = (const float*)d_in[17];
    float* out = (float*)d_out;

    const int* src  = ei;
    const int* dstv = ei + N_EDGES;

    // workspace layout
    char* ws = (char*)d_ws;
    size_t off = 0;
    int* cnt               = (int*)(ws + off); off += ((size_t)N_NODES * 4 + 511) & ~511ull;
    unsigned short* bucket = (unsigned short*)(ws + off); off += (size_t)N_NODES * CAP * 2;
    f16* xh     = (f16*)(ws + off); off += (size_t)N_NODES * 128 * 2;
    f16* meanb  = (f16*)(ws + off); off += (size_t)N_NODES * 128 * 2;
    f16* y2     = (f16*)(ws + off); off += (size_t)N_NODES * 128 * 2;
    f16* W1     = (f16*)(ws + off); off += (size_t)128 * 256 * 2;
    f16* W2cat  = (f16*)(ws + off); off += (size_t)128 * 128 * 2;

    // --- fused bucket build + f16 conversion (thread-level overlap) ---
    zero_cnt_kernel<<<(N_NODES / 4 + 255) / 256, 256, 0, stream>>>(cnt);
    build_fused_kernel<<<EDGE_BLOCKS + 4, 256, 0, stream>>>(
        src, dstv, cnt, bucket, x, w1l, w1r, w2l, w2r, xh, W1, W2cat);

    // --- layer 1 + layer-2 pre-transform (fused) ---
    agg_mean_f16_kernel<<<N_NODES / 8, 256, 0, stream>>>(xh, cnt, bucket, meanb);
    sage1_y2_kernel<<<(N_NODES + 127) / 128, 256, 0, stream>>>(
        meanb, xh, W1, b1l, bn1_g, bn1_b, bn1_m, bn1_v, W2cat, y2);

    // --- layer-2 aggregate + BN2 + ReLU + head (fused) ---
    agg2_head_kernel<<<N_NODES / 16, 256, 0, stream>>>(
        y2, cnt, bucket, b2l, bn2_g, bn2_b, bn2_m, bn2_v, head_w, head_b, out);
}

// Round 17
// 143.614 us; speedup vs baseline: 1.0181x; 1.0181x over previous
//
#include <hip/hip_runtime.h>

typedef _Float16 f16;
typedef _Float16 f16x4 __attribute__((ext_vector_type(4)));
typedef _Float16 f16x8 __attribute__((ext_vector_type(8)));
typedef float f32x4 __attribute__((ext_vector_type(4)));

#define N_NODES 50000
#define N_EDGES 800000
#define N_CLASSES 10
#define CAP 64           // per-node bucket capacity; deg~Poisson(16), P(>=64)~e^-128
#define EDGE_BLOCKS ((N_EDGES + 255) / 256)        // 3125

// ---------------------------------------------------------------------------
// Zero the degree counters (~2us; rocclr fillBuffer was ~40us)
// ---------------------------------------------------------------------------
__global__ void zero_cnt_kernel(int* __restrict__ cnt) {
    int i = blockIdx.x * 256 + threadIdx.x;
    if (i < N_NODES / 4) ((int4*)cnt)[i] = make_int4(0, 0, 0, 0);
}

// ---------------------------------------------------------------------------
// Fused build (R11-proven): even blocks fill buckets (atomic-latency), odd
// blocks convert x to f16 (bandwidth) — interleave keeps both co-resident.
// Build floor ~55us = 800k atomic-with-return at ~19 Gops/s (R7/R12/R15
// three-way confirmed); convert rides in the latency shadow.
// ---------------------------------------------------------------------------
__global__ void build_fused_kernel(const int* __restrict__ src, const int* __restrict__ dst,
                                   int* __restrict__ cnt, unsigned short* __restrict__ bucket,
                                   const float* __restrict__ x,
                                   const float* __restrict__ w1l, const float* __restrict__ w1r,
                                   const float* __restrict__ w2l, const float* __restrict__ w2r,
                                   f16* __restrict__ xh, f16* __restrict__ W1, f16* __restrict__ W2cat) {
    int bid = blockIdx.x;
    if (bid < 2 * EDGE_BLOCKS) {
        int half = bid >> 1;
        if ((bid & 1) == 0) {
            int e = half * 256 + threadIdx.x;
            if (e < N_EDGES) {
                int d = dst[e];
                int s = atomicAdd(&cnt[d], 1);
                if (s < CAP) bucket[(long long)d * CAP + s] = (unsigned short)src[e];
            }
        } else {
            long long base = ((long long)half * 256 + threadIdx.x) * 8;
            float4 a = *(const float4*)(x + base);
            float4 b = *(const float4*)(x + base + 4);
            f16x8 o;
            o[0] = (f16)a.x; o[1] = (f16)a.y; o[2] = (f16)a.z; o[3] = (f16)a.w;
            o[4] = (f16)b.x; o[5] = (f16)b.y; o[6] = (f16)b.z; o[7] = (f16)b.w;
            *(f16x8*)(xh + base) = o;
        }
    } else {
        int wt = (bid - 2 * EDGE_BLOCKS) * 256 + threadIdx.x;   // 0..1023
        for (int idx = wt; idx < 128 * 256; idx += 1024) {
            int n = idx >> 8, k = idx & 255;
            W1[idx] = (f16)(k < 128 ? w1l[n * 128 + k] : w1r[n * 128 + k - 128]);
        }
        for (int idx = wt; idx < 128 * 128; idx += 1024) {
            int n = idx >> 7, k = idx & 127;
            W2cat[idx] = (f16)(n < 64 ? w2l[n * 128 + k] : w2r[(n - 64) * 128 + k]);
        }
    }
}

// ---------------------------------------------------------------------------
// Layer-1 aggregation (R11-proven): 2 nodes/wave, 32 lanes x f16x4 (8B).
// ---------------------------------------------------------------------------
__global__ void agg_mean_f16_kernel(const f16* __restrict__ feat,
                                    const int* __restrict__ cnt,
                                    const unsigned short* __restrict__ bucket,
                                    f16* __restrict__ outb) {
    int node = blockIdx.x * 8 + (threadIdx.x >> 5);
    int l  = threadIdx.x & 31;
    int bl = threadIdx.x & 32;
    int deg = cnt[node];
    int n_it = deg < CAP ? deg : CAP;
    const unsigned short* b = bucket + (long long)node * CAP;
    int my0 = (l < n_it)      ? (int)b[l]      : 0;
    int my1 = (32 + l < n_it) ? (int)b[32 + l] : 0;
    const f16x4* f4 = (const f16x4*)feat;
    float a0 = 0.f, a1 = 0.f, a2 = 0.f, a3 = 0.f;
    int j = 0;
    int lim0 = n_it < 32 ? n_it : 32;
    for (; j + 8 <= lim0; j += 8) {
        f16x4 v0 = f4[(long long)__shfl(my0, bl + j + 0) * 32 + l];
        f16x4 v1 = f4[(long long)__shfl(my0, bl + j + 1) * 32 + l];
        f16x4 v2 = f4[(long long)__shfl(my0, bl + j + 2) * 32 + l];
        f16x4 v3 = f4[(long long)__shfl(my0, bl + j + 3) * 32 + l];
        f16x4 v4 = f4[(long long)__shfl(my0, bl + j + 4) * 32 + l];
        f16x4 v5 = f4[(long long)__shfl(my0, bl + j + 5) * 32 + l];
        f16x4 v6 = f4[(long long)__shfl(my0, bl + j + 6) * 32 + l];
        f16x4 v7 = f4[(long long)__shfl(my0, bl + j + 7) * 32 + l];
        a0 += (((float)v0[0] + (float)v1[0]) + ((float)v2[0] + (float)v3[0]))
            + (((float)v4[0] + (float)v5[0]) + ((float)v6[0] + (float)v7[0]));
        a1 += (((float)v0[1] + (float)v1[1]) + ((float)v2[1] + (float)v3[1]))
            + (((float)v4[1] + (float)v5[1]) + ((float)v6[1] + (float)v7[1]));
        a2 += (((float)v0[2] + (float)v1[2]) + ((float)v2[2] + (float)v3[2]))
            + (((float)v4[2] + (float)v5[2]) + ((float)v6[2] + (float)v7[2]));
        a3 += (((float)v0[3] + (float)v1[3]) + ((float)v2[3] + (float)v3[3]))
            + (((float)v4[3] + (float)v5[3]) + ((float)v6[3] + (float)v7[3]));
    }
    for (; j < lim0; j++) {
        f16x4 v = f4[(long long)__shfl(my0, bl + j) * 32 + l];
        a0 += (float)v[0]; a1 += (float)v[1]; a2 += (float)v[2]; a3 += (float)v[3];
    }
    for (; j + 8 <= n_it; j += 8) {
        f16x4 v0 = f4[(long long)__shfl(my1, bl + j - 32 + 0) * 32 + l];
        f16x4 v1 = f4[(long long)__shfl(my1, bl + j - 32 + 1) * 32 + l];
        f16x4 v2 = f4[(long long)__shfl(my1, bl + j - 32 + 2) * 32 + l];
        f16x4 v3 = f4[(long long)__shfl(my1, bl + j - 32 + 3) * 32 + l];
        f16x4 v4 = f4[(long long)__shfl(my1, bl + j - 32 + 4) * 32 + l];
        f16x4 v5 = f4[(long long)__shfl(my1, bl + j - 32 + 5) * 32 + l];
        f16x4 v6 = f4[(long long)__shfl(my1, bl + j - 32 + 6) * 32 + l];
        f16x4 v7 = f4[(long long)__shfl(my1, bl + j - 32 + 7) * 32 + l];
        a0 += (((float)v0[0] + (float)v1[0]) + ((float)v2[0] + (float)v3[0]))
            + (((float)v4[0] + (float)v5[0]) + ((float)v6[0] + (float)v7[0]));
        a1 += (((float)v0[1] + (float)v1[1]) + ((float)v2[1] + (float)v3[1]))
            + (((float)v4[1] + (float)v5[1]) + ((float)v6[1] + (float)v7[1]));
        a2 += (((float)v0[2] + (float)v1[2]) + ((float)v2[2] + (float)v3[2]))
            + (((float)v4[2] + (float)v5[2]) + ((float)v6[2] + (float)v7[2]));
        a3 += (((float)v0[3] + (float)v1[3]) + ((float)v2[3] + (float)v3[3]))
            + (((float)v4[3] + (float)v5[3]) + ((float)v6[3] + (float)v7[3]));
    }
    for (; j < n_it; j++) {
        f16x4 v = f4[(long long)__shfl(my1, bl + j - 32) * 32 + l];
        a0 += (float)v[0]; a1 += (float)v[1]; a2 += (float)v[2]; a3 += (float)v[3];
    }
    float inv = 1.f / fmaxf((float)deg, 1.f);
    f16x4 r;
    r[0] = (f16)(a0 * inv); r[1] = (f16)(a1 * inv);
    r[2] = (f16)(a2 * inv); r[3] = (f16)(a3 * inv);
    ((f16x4*)outb)[(long long)node * 32 + l] = r;
}

// ---------------------------------------------------------------------------
// Fused layer-1 + layer-2 pre-transform (R13-proven):
// Stage 1: h1 = relu(bn1(mean@W1l^T+b1+x@W1r^T)) -> per-wave LDS tile
// Stage 2: y2 = [h1@W2l^T | h1@W2r^T] -> global (h1 never hits HBM).
// ---------------------------------------------------------------------------
__global__ __launch_bounds__(256) void sage1_y2_kernel(
    const f16* __restrict__ Am, const f16* __restrict__ Ax,
    const f16* __restrict__ W1,
    const float* __restrict__ bias, const float* __restrict__ gamma,
    const float* __restrict__ beta, const float* __restrict__ bmean,
    const float* __restrict__ bvar,
    const f16* __restrict__ W2cat,  // [128][128]
    f16* __restrict__ y2) {
    __shared__ f16 ldsA[4][32][136];

    int tid  = threadIdx.x;
    int wave = tid >> 6;
    int lane = tid & 63;
    int m_base = blockIdx.x * 128 + wave * 32;
    int lrow = lane & 15;
    int lchunk = lane >> 4;

    f32x4 acc[2][8] = {};

#pragma unroll
    for (int phase = 0; phase < 2; phase++) {
        const f16* A = phase ? Ax : Am;
        const f16* Wp = W1 + phase * 128;
        f16x8 afrag[4][2];
#pragma unroll
        for (int kc = 0; kc < 4; kc++)
#pragma unroll
            for (int mf = 0; mf < 2; mf++) {
                int row = m_base + mf * 16 + lrow;
                row = row < N_NODES ? row : N_NODES - 1;
                afrag[kc][mf] = *(const f16x8*)(A + (long long)row * 128 + kc * 32 + lchunk * 8);
            }
#pragma unroll
        for (int nf = 0; nf < 8; nf++)
#pragma unroll
            for (int kc = 0; kc < 4; kc++) {
                f16x8 b = *(const f16x8*)(Wp + (long long)(nf * 16 + lrow) * 256
                                          + kc * 32 + lchunk * 8);
                acc[0][nf] = __builtin_amdgcn_mfma_f32_16x16x32_f16(afrag[kc][0], b, acc[0][nf], 0, 0, 0);
                acc[1][nf] = __builtin_amdgcn_mfma_f32_16x16x32_f16(afrag[kc][1], b, acc[1][nf], 0, 0, 0);
            }
    }

    // BN1 + ReLU -> per-wave LDS tile
#pragma unroll
    for (int nf = 0; nf < 8; nf++) {
        int n = nf * 16 + lrow;
        float mul = gamma[n] * rsqrtf(bvar[n] + 1e-5f);
        float add = (bias[n] - bmean[n]) * mul + beta[n];
#pragma unroll
        for (int mf = 0; mf < 2; mf++)
#pragma unroll
            for (int r = 0; r < 4; r++) {
                int rloc = mf * 16 + lchunk * 4 + r;
                ldsA[wave][rloc][n] = (f16)fmaxf(fmaf(acc[mf][nf][r], mul, add), 0.f);
            }
    }

    // Stage 2: y2 = h1_tile @ W2cat^T (K=128)
#pragma unroll
    for (int nf2 = 0; nf2 < 8; nf2++) {
        f32x4 acc2[2] = {};
#pragma unroll
        for (int kc = 0; kc < 4; kc++) {
            f16x8 b2 = *(const f16x8*)(W2cat + (long long)(nf2 * 16 + lrow) * 128
                                       + kc * 32 + lchunk * 8);
            f16x8 a0 = *(const f16x8*)&ldsA[wave][lrow][kc * 32 + lchunk * 8];
            f16x8 a1 = *(const f16x8*)&ldsA[wave][16 + lrow][kc * 32 + lchunk * 8];
            acc2[0] = __builtin_amdgcn_mfma_f32_16x16x32_f16(a0, b2, acc2[0], 0, 0, 0);
            acc2[1] = __builtin_amdgcn_mfma_f32_16x16x32_f16(a1, b2, acc2[1], 0, 0, 0);
        }
        int n = nf2 * 16 + lrow;
#pragma unroll
        for (int mf = 0; mf < 2; mf++)
#pragma unroll
            for (int r = 0; r < 4; r++) {
                int m = m_base + mf * 16 + lchunk * 4 + r;
                if (m < N_NODES) y2[(long long)m * 128 + n] = (f16)acc2[mf][r];
            }
    }
}

// ---------------------------------------------------------------------------
// Fused layer-2 aggregation + BN2 + ReLU + head (R14-proven). 16 nodes/block,
// 3125 blocks. No LDS, no syncthreads.
// ---------------------------------------------------------------------------
__global__ void agg2_head_kernel(const f16* __restrict__ y2,
                                 const int* __restrict__ cnt,
                                 const unsigned short* __restrict__ bucket,
                                 const float* __restrict__ b2,
                                 const float* __restrict__ gamma,
                                 const float* __restrict__ beta,
                                 const float* __restrict__ bmean,
                                 const float* __restrict__ bvar,
                                 const float* __restrict__ hw,
                                 const float* __restrict__ hb,
                                 float* __restrict__ outp) {
    int node = blockIdx.x * 16 + (threadIdx.x >> 4);
    int l  = threadIdx.x & 15;
    int bl = threadIdx.x & 48;
    int deg = cnt[node];
    int n_it = deg < CAP ? deg : CAP;
    const unsigned short* b = bucket + (long long)node * CAP;
    int my0 = (l < n_it)      ? (int)b[l]      : 0;
    int my1 = (16 + l < n_it) ? (int)b[16 + l] : 0;
    int my2 = (32 + l < n_it) ? (int)b[32 + l] : 0;
    int my3 = (48 + l < n_it) ? (int)b[48 + l] : 0;
    const f16x4* f4 = (const f16x4*)y2;
    float a0 = 0.f, a1 = 0.f, a2 = 0.f, a3 = 0.f;
    int j = 0;

#define AGG_SEC(MYREG, BASE)                                                     \
    {                                                                            \
        int lim = n_it < (BASE + 16) ? n_it : (BASE + 16);                       \
        for (; j + 8 <= lim; j += 8) {                                           \
            f16x4 v0 = f4[(long long)__shfl(MYREG, bl + j - BASE + 0) * 32 + l]; \
            f16x4 v1 = f4[(long long)__shfl(MYREG, bl + j - BASE + 1) * 32 + l]; \
            f16x4 v2 = f4[(long long)__shfl(MYREG, bl + j - BASE + 2) * 32 + l]; \
            f16x4 v3 = f4[(long long)__shfl(MYREG, bl + j - BASE + 3) * 32 + l]; \
            f16x4 v4 = f4[(long long)__shfl(MYREG, bl + j - BASE + 4) * 32 + l]; \
            f16x4 v5 = f4[(long long)__shfl(MYREG, bl + j - BASE + 5) * 32 + l]; \
            f16x4 v6 = f4[(long long)__shfl(MYREG, bl + j - BASE + 6) * 32 + l]; \
            f16x4 v7 = f4[(long long)__shfl(MYREG, bl + j - BASE + 7) * 32 + l]; \
            a0 += (((float)v0[0] + (float)v1[0]) + ((float)v2[0] + (float)v3[0]))\
                + (((float)v4[0] + (float)v5[0]) + ((float)v6[0] + (float)v7[0]));\
            a1 += (((float)v0[1] + (float)v1[1]) + ((float)v2[1] + (float)v3[1]))\
                + (((float)v4[1] + (float)v5[1]) + ((float)v6[1] + (float)v7[1]));\
            a2 += (((float)v0[2] + (float)v1[2]) + ((float)v2[2] + (float)v3[2]))\
                + (((float)v4[2] + (float)v5[2]) + ((float)v6[2] + (float)v7[2]));\
            a3 += (((float)v0[3] + (float)v1[3]) + ((float)v2[3] + (float)v3[3]))\
                + (((float)v4[3] + (float)v5[3]) + ((float)v6[3] + (float)v7[3]));\
        }                                                                        \
        for (; j < lim; j++) {                                                   \
            f16x4 v = f4[(long long)__shfl(MYREG, bl + j - BASE) * 32 + l];      \
            a0 += (float)v[0]; a1 += (float)v[1];                                \
            a2 += (float)v[2]; a3 += (float)v[3];                                \
        }                                                                        \
    }

    AGG_SEC(my0, 0)
    AGG_SEC(my1, 16)
    AGG_SEC(my2, 32)
    AGG_SEC(my3, 48)
#undef AGG_SEC

    // BN2 + ReLU in f32 (channels 4l..4l+3 of this node)
    float inv = 1.f / fmaxf((float)deg, 1.f);
    f16x4 yr = f4[(long long)node * 32 + 16 + l];   // y2r quad
    float h[4];
#pragma unroll
    for (int i = 0; i < 4; i++) {
        int n = l * 4 + i;
        float mul = gamma[n] * rsqrtf(bvar[n] + 1e-5f);
        float add = (b2[n] - bmean[n]) * mul + beta[n];
        float a = (i == 0 ? a0 : i == 1 ? a1 : i == 2 ? a2 : a3);
        h[i] = fmaxf(fmaf(a * inv + (float)yr[i], mul, add), 0.f);
    }

    // head: 10 logits, 16-lane group reduce per class
#pragma unroll
    for (int c = 0; c < N_CLASSES; c++) {
        const float* w = hw + c * 64 + l * 4;
        float p = h[0] * w[0] + h[1] * w[1] + h[2] * w[2] + h[3] * w[3];
        p += __shfl_xor(p, 8);
        p += __shfl_xor(p, 4);
        p += __shfl_xor(p, 2);
        p += __shfl_xor(p, 1);
        if (l == c) outp[(long long)node * N_CLASSES + c] = p + hb[c];
    }
}

// ---------------------------------------------------------------------------
extern "C" void kernel_launch(void* const* d_in, const int* in_sizes, int n_in,
                              void* d_out, int out_size, void* d_ws, size_t ws_size,
                              hipStream_t stream) {
    const float* x      = (const float*)d_in[0];
    const int*   ei     = (const int*)d_in[1];
    const float* w1l    = (const float*)d_in[2];
    const float* b1l    = (const float*)d_in[3];
    const float* w1r    = (const float*)d_in[4];
    const float* bn1_g  = (const float*)d_in[5];
    const float* bn1_b  = (const float*)d_in[6];
    const float* bn1_m  = (const float*)d_in[7];
    const float* bn1_v  = (const float*)d_in[8];
    const float* w2l    = (const float*)d_in[9];
    const float* b2l    = (const float*)d_in[10];
    const float* w2r    = (const float*)d_in[11];
    const float* bn2_g  = (const float*)d_in[12];
    const float* bn2_b  = (const float*)d_in[13];
    const float* bn2_m  = (const float*)d_in[14];
    const float* bn2_v  = (const float*)d_in[15];
    const float* head_w = (const float*)d_in[16];
    const float* head_b = (const float*)d_in[17];
    float* out = (float*)d_out;

    const int* src  = ei;
    const int* dstv = ei + N_EDGES;

    // workspace layout
    char* ws = (char*)d_ws;
    size_t off = 0;
    int* cnt               = (int*)(ws + off); off += ((size_t)N_NODES * 4 + 511) & ~511ull;
    unsigned short* bucket = (unsigned short*)(ws + off); off += (size_t)N_NODES * CAP * 2;
    f16* xh     = (f16*)(ws + off); off += (size_t)N_NODES * 128 * 2;
    f16* meanb  = (f16*)(ws + off); off += (size_t)N_NODES * 128 * 2;
    f16* y2     = (f16*)(ws + off); off += (size_t)N_NODES * 128 * 2;
    f16* W1     = (f16*)(ws + off); off += (size_t)128 * 256 * 2;
    f16* W2cat  = (f16*)(ws + off); off += (size_t)128 * 128 * 2;

    // --- fused bucket build + f16 conversion ---
    zero_cnt_kernel<<<(N_NODES / 4 + 255) / 256, 256, 0, stream>>>(cnt);
    build_fused_kernel<<<2 * EDGE_BLOCKS + 4, 256, 0, stream>>>(
        src, dstv, cnt, bucket, x, w1l, w1r, w2l, w2r, xh, W1, W2cat);

    // --- layer 1 + layer-2 pre-transform (fused) ---
    agg_mean_f16_kernel<<<N_NODES / 8, 256, 0, stream>>>(xh, cnt, bucket, meanb);
    sage1_y2_kernel<<<(N_NODES + 127) / 128, 256, 0, stream>>>(
        meanb, xh, W1, b1l, bn1_g, bn1_b, bn1_m, bn1_v, W2cat, y2);

    // --- layer-2 aggregate + BN2 + ReLU + head (fused) ---
    agg2_head_kernel<<<N_NODES / 16, 256, 0, stream>>>(
        y2, cnt, bucket, b2l, bn2_g, bn2_b, bn2_m, bn2_v, head_w, head_b, out);
}